// Round 1
// baseline (277.932 us; speedup 1.0000x reference)
//
#include <hip/hip_runtime.h>

// RandomShiftsAug: out[n][c][oh][ow] = x[n][c][wrap(max(ky+oh-4,0))][clamp(kx+ow-4,0,419)]
// Pure memory-bound shifted copy. ~325 MB HBM traffic -> ~52us roofline.

constexpr int N     = 128;
constexpr int C     = 9;
constexpr int H     = 84;
constexpr int W     = 420;
constexpr int PAD   = 4;
constexpr int OUT_H = 84;
constexpr int ROW_V4 = W / 4;                      // 105 float4 per output row
constexpr int TOTAL_V4 = N * C * OUT_H * ROW_V4;   // 10,160,640

__global__ __launch_bounds__(256)
void RandomShiftsAug_kernel(const float* __restrict__ x,
                            const int*   __restrict__ shift,
                            float4*      __restrict__ out) {
    const int stride = gridDim.x * blockDim.x;
    for (int i = blockIdx.x * blockDim.x + threadIdx.x; i < TOTAL_V4; i += stride) {
        // decompose i -> (row_id, lane); row_id -> (nc, oh); nc -> n
        const int row_id = i / ROW_V4;               // const-div -> magic mul
        const int lane   = i - row_id * ROW_V4;
        const int ow0    = lane * 4;
        const int oh     = row_id % OUT_H;
        const int nc     = row_id / OUT_H;           // n*C + c, matches x layout
        const int n      = nc / C;

        const int kx = shift[2 * n]     - PAD;       // in [-4, 4]
        const int ky = shift[2 * n + 1];             // in [0, 8]

        int r = ky + oh - PAD;                       // in [-4, 87]
        r = r < 0 ? 0 : r;                           // edge pad (top)
        if (r >= H) r -= H;                          // vertical tile wrap

        const float* __restrict__ src = x + ((long long)nc * H + r) * W;

        const int c0 = ow0 + kx;
        float4 v;
        if (c0 >= 0 && c0 + 3 < W) {
            // interior fast path: contiguous 4 scalar loads (unaligned by kx)
            v.x = src[c0];
            v.y = src[c0 + 1];
            v.z = src[c0 + 2];
            v.w = src[c0 + 3];
        } else {
            // edge: branchless clamp per element (left/right edge replicate)
            const int a0 = min(max(c0,     0), W - 1);
            const int a1 = min(max(c0 + 1, 0), W - 1);
            const int a2 = min(max(c0 + 2, 0), W - 1);
            const int a3 = min(max(c0 + 3, 0), W - 1);
            v.x = src[a0];
            v.y = src[a1];
            v.z = src[a2];
            v.w = src[a3];
        }
        out[i] = v;
    }
}

extern "C" void kernel_launch(void* const* d_in, const int* in_sizes, int n_in,
                              void* d_out, int out_size, void* d_ws, size_t ws_size,
                              hipStream_t stream) {
    const float* x     = (const float*)d_in[0];
    const int*   shift = (const int*)d_in[1];
    float4*      out   = (float4*)d_out;

    const int block = 256;
    const int grid  = 2048;   // 8 blocks/CU, grid-stride covers TOTAL_V4
    RandomShiftsAug_kernel<<<grid, block, 0, stream>>>(x, shift, out);
}

// Round 2
// 273.594 us; speedup vs baseline: 1.0159x; 1.0159x over previous
//
#include <hip/hip_runtime.h>

// RandomShiftsAug: out[n][c][oh][ow] = x[n][c][wrap(max(ky+oh-4,0))][clamp(kx+ow-4,0,419)]
// Memory-bound shifted copy, ~325 MB HBM traffic -> ~52us roofline.
//
// Key fix vs R1: interior path now does TWO ALIGNED dwordx4 loads per thread
// (uniform float4 index offset, fully coalesced; neighbor-lane overlap is an
// L1 hit) + a cndmask select on rem = (4*lane+kx)&3, instead of 4 scalar
// dword loads at 16B inter-lane stride (4x VMEM instr + 4x line requests).

constexpr int N     = 128;
constexpr int C     = 9;
constexpr int H     = 84;
constexpr int W     = 420;
constexpr int PAD   = 4;
constexpr int OUT_H = 84;
constexpr int ROW_V4   = W / 4;                    // 105 float4 per row
constexpr int TOTAL_V4 = N * C * OUT_H * ROW_V4;   // 10,160,640

__global__ __launch_bounds__(256)
void RandomShiftsAug_kernel(const float* __restrict__ x,
                            const int*   __restrict__ shift,
                            float4*      __restrict__ out) {
    const int stride = gridDim.x * blockDim.x;
    for (int i = blockIdx.x * blockDim.x + threadIdx.x; i < TOTAL_V4; i += stride) {
        const int row_id = i / ROW_V4;               // const-div -> magic mul
        const int lane   = i - row_id * ROW_V4;      // 0..104
        const int oh     = row_id % OUT_H;
        const int nc     = row_id / OUT_H;           // n*C + c (matches x layout)
        const int n      = nc / C;

        const int kx = shift[2 * n]     - PAD;       // [-4, 4]
        const int ky = shift[2 * n + 1];             // [0, 8]

        int r = ky + oh - PAD;                       // [-4, 87]
        r = r < 0 ? 0 : r;                           // top edge replicate
        if (r >= H) r -= H;                          // vertical tile wrap

        const float* __restrict__ src = x + ((size_t)nc * H + r) * W;
        const int c0 = lane * 4 + kx;

        float4 v;
        if (c0 >= 0 && c0 <= W - 4) {
            // interior: two aligned float4 loads, then select window [rem, rem+3]
            const float4* __restrict__ srcv = (const float4*)src;  // row base is 16B-aligned (W*4 = 1680 = 105*16)
            const int i0 = c0 >> 2;                   // = lane + floor(kx/4), uniform offset
            const int i1 = min(i0 + 1, ROW_V4 - 1);   // clamp: avoids OOB read past last row
            const float4 A = srcv[i0];
            const float4 B = srcv[i1];
            const int rem = c0 & 3;                   // 0..3 (wave-uniform except sample-straddling waves)
            const float s0 = A.x, s1 = A.y, s2 = A.z, s3 = A.w;
            const float s4 = B.x, s5 = B.y, s6 = B.z, s7 = B.w;
            const bool r1 = (rem == 1), r2 = (rem == 2), r3 = (rem == 3);
            v.x = r3 ? s3 : (r2 ? s2 : (r1 ? s1 : s0));
            v.y = r3 ? s4 : (r2 ? s3 : (r1 ? s2 : s1));
            v.z = r3 ? s5 : (r2 ? s4 : (r1 ? s3 : s2));
            v.w = r3 ? s6 : (r2 ? s5 : (r1 ? s4 : s3));
        } else {
            // row edges (~2% of threads): scalar loads with clamp-replicate
            const int a0 = min(max(c0,     0), W - 1);
            const int a1 = min(max(c0 + 1, 0), W - 1);
            const int a2 = min(max(c0 + 2, 0), W - 1);
            const int a3 = min(max(c0 + 3, 0), W - 1);
            v.x = src[a0];
            v.y = src[a1];
            v.z = src[a2];
            v.w = src[a3];
        }
        out[i] = v;
    }
}

extern "C" void kernel_launch(void* const* d_in, const int* in_sizes, int n_in,
                              void* d_out, int out_size, void* d_ws, size_t ws_size,
                              hipStream_t stream) {
    const float* x     = (const float*)d_in[0];
    const int*   shift = (const int*)d_in[1];
    float4*      out   = (float4*)d_out;

    const int block = 256;
    const int grid  = 2048;   // 8 blocks/CU, grid-stride over TOTAL_V4
    RandomShiftsAug_kernel<<<grid, block, 0, stream>>>(x, shift, out);
}

// Round 3
// 270.363 us; speedup vs baseline: 1.0280x; 1.0120x over previous
//
#include <hip/hip_runtime.h>

// RandomShiftsAug: out[n][c][oh][ow] = x[n][c][wrap(max(ky+oh-4,0))][clamp(kx+ow-4,0,419)]
// Memory-bound shifted copy: 162.5 MB read + 162.5 MB write -> ~52us kernel roofline.
// Headline dur_us also contains ~170-200us of harness poison/restore overhead
// (profile top-5 is all fillBufferAligned @ ~98us; our kernel is below the cutoff).
//
// R3 changes vs R2:
//  - nontemporal stores for out (write-once stream; keep L2/LLC free for x reads --
//    x is 150.6 MB and fits the 256 MB LLC)
//  - one-pass grid (39,690 blocks x 256 thr, exactly one float4/thread, no
//    grid-stride loop): shortest dependent chain, 158,760 waves for latency hiding.
//  - interior path unchanged: two ALIGNED dwordx4 loads (uniform v4-offset, fully
//    coalesced, neighbor-lane overlap hits L1) + cndmask select on (4*lane+kx)&3.

constexpr int N     = 128;
constexpr int C     = 9;
constexpr int H     = 84;
constexpr int W     = 420;
constexpr int PAD   = 4;
constexpr int OUT_H = 84;
constexpr int ROW_V4   = W / 4;                    // 105 float4 per row
constexpr int TOTAL_V4 = N * C * OUT_H * ROW_V4;   // 10,160,640 = 39,690 * 256

typedef float f32x4 __attribute__((ext_vector_type(4)));

__global__ __launch_bounds__(256)
void RandomShiftsAug_kernel(const float* __restrict__ x,
                            const int*   __restrict__ shift,
                            f32x4*       __restrict__ out) {
    const int i = blockIdx.x * 256 + threadIdx.x;   // exact cover, no loop

    const int row_id = i / ROW_V4;               // const-div -> magic mul
    const int lane   = i - row_id * ROW_V4;      // 0..104
    const int nc     = row_id / OUT_H;           // n*C + c (matches x layout)
    const int oh     = row_id - nc * OUT_H;
    const int n      = nc / C;

    const int kx = shift[2 * n]     - PAD;       // [-4, 4]
    const int ky = shift[2 * n + 1];             // [0, 8]

    int r = ky + oh - PAD;                       // [-4, 87]
    r = r < 0 ? 0 : r;                           // top edge replicate
    if (r >= H) r -= H;                          // vertical tile wrap

    const float* __restrict__ src = x + ((size_t)nc * H + r) * W;
    const int c0 = lane * 4 + kx;

    f32x4 v;
    if (c0 >= 0 && c0 <= W - 4) {
        // interior: two aligned float4 loads, then select window [rem, rem+3]
        const f32x4* __restrict__ srcv = (const f32x4*)src;  // row base 16B-aligned (W*4 = 1680)
        const int i0 = c0 >> 2;                   // = lane + floor(kx/4), wave-uniform offset
        const int i1 = min(i0 + 1, ROW_V4 - 1);   // clamp: no OOB past last row
        const f32x4 A = srcv[i0];
        const f32x4 B = srcv[i1];
        const int rem = c0 & 3;                   // 0..3
        const float s0 = A.x, s1 = A.y, s2 = A.z, s3 = A.w;
        const float s4 = B.x, s5 = B.y, s6 = B.z;
        const bool r1 = (rem == 1), r2 = (rem == 2), r3 = (rem == 3);
        v.x = r3 ? s3 : (r2 ? s2 : (r1 ? s1 : s0));
        v.y = r3 ? s4 : (r2 ? s3 : (r1 ? s2 : s1));
        v.z = r3 ? s5 : (r2 ? s4 : (r1 ? s3 : s2));
        v.w = r3 ? s6 : (r2 ? s5 : (r1 ? s4 : s3));
    } else {
        // row edges (~2% of threads): scalar loads with clamp-replicate
        const int a0 = min(max(c0,     0), W - 1);
        const int a1 = min(max(c0 + 1, 0), W - 1);
        const int a2 = min(max(c0 + 2, 0), W - 1);
        const int a3 = min(max(c0 + 3, 0), W - 1);
        v.x = src[a0];
        v.y = src[a1];
        v.z = src[a2];
        v.w = src[a3];
    }
    __builtin_nontemporal_store(v, &out[i]);     // write-once stream: don't pollute L2/LLC
}

extern "C" void kernel_launch(void* const* d_in, const int* in_sizes, int n_in,
                              void* d_out, int out_size, void* d_ws, size_t ws_size,
                              hipStream_t stream) {
    const float* x     = (const float*)d_in[0];
    const int*   shift = (const int*)d_in[1];
    f32x4*       out   = (f32x4*)d_out;

    const int block = 256;
    const int grid  = TOTAL_V4 / block;          // 39,690 blocks, exact cover
    RandomShiftsAug_kernel<<<grid, block, 0, stream>>>(x, shift, out);
}